// Round 3
// baseline (247.784 us; speedup 1.0000x reference)
//
#include <hip/hip_runtime.h>
#include <math.h>

// CompetingRisks: B=4096, D=128, R=2. 16 tasks/block (shared r), 16 lanes/task.
// Phase 1 (NEW): cooperative coalesced staging of w1r into LDS, per-thread
//   P-dots read via ds_read_b128 (broadcast across the 16 groups).
// Phase 2: dopri5; f-eval = 17 units/lane + 4-op DPP reduce + fast softplus.

#define B_ 4096
#define R_ 2
#define D_ 128
#define IN_ 130
#define HID_ 260
#define MAXSTEPS_ 16
#define H0_ 0.05f
#define RTOL_ 1e-3f
#define ATOL_ 1e-3f
#define NU_ 17      // units per lane: j = sub + 16*i, i in [0,17)

#define WROWS_ 272  // covers j up to 271 (sub+256); rows >=260 zeroed
#define WSTR_ 36    // LDS row stride in dwords (32 data + 4 pad -> 2-way banks)
#define ZSTR_ 132   // z row stride in dwords (128 + 4 pad)

// Sum across a 16-lane row; result uniform in all 16 lanes. Pure DPP (VALU).
__device__ __forceinline__ float dpp_add16(float v) {
    int y;
    y = __builtin_amdgcn_update_dpp(0, __float_as_int(v), 0xB1, 0xF, 0xF, false);  // quad_perm xor1
    v += __int_as_float(y);
    y = __builtin_amdgcn_update_dpp(0, __float_as_int(v), 0x4E, 0xF, 0xF, false);  // quad_perm xor2
    v += __int_as_float(y);
    y = __builtin_amdgcn_update_dpp(0, __float_as_int(v), 0x124, 0xF, 0xF, false); // row_ror:4
    v += __int_as_float(y);
    y = __builtin_amdgcn_update_dpp(0, __float_as_int(v), 0x128, 0xF, 0xF, false); // row_ror:8
    v += __int_as_float(y);
    return v;
}

// softplus(x) = max(x,0) + log1p(exp(-|x|)) via native v_exp_f32 / v_log_f32
__device__ __forceinline__ float softplus_fast(float x) {
    const float q  = exp2f(-1.4426950408889634f * fabsf(x));
    const float lg = 0.6931471805599453f * log2f(1.0f + q);
    return fmaxf(x, 0.0f) + lg;
}

__global__ __launch_bounds__(256) void cr_kernel(
    const float* __restrict__ z, const float* __restrict__ t_eval,
    const float* __restrict__ w1, const float* __restrict__ b1,
    const float* __restrict__ w2, const float* __restrict__ b2,
    float* __restrict__ out)
{
    __shared__ float sW[WROWS_ * WSTR_];   // 39168 B
    __shared__ float sZ[16 * ZSTR_];       //  8448 B

    const int t   = threadIdx.x;
    const int sub = t & 15;                // lane within 16-lane group
    const int g   = t >> 4;                // group (task) within block: 0..15
    const int r   = blockIdx.x >> 8;       // 512 blocks: 256 per risk
    const int b0  = (blockIdx.x & 255) * 16;
    const int b   = b0 + g;

    const float te = t_eval[b];
    const float* w1r = w1 + r * HID_ * IN_;

    // ---- stage z tile: 16 rows x 128, coalesced float4 ----
#pragma unroll
    for (int q = 0; q < 2; ++q) {
        const int idx = q * 256 + t;           // 0..511
        const int zb  = idx >> 5;              // 0..15
        const int kq  = (idx & 31) << 2;       // 0,4,...,124
        const float4 v = *(const float4*)(z + (b0 + zb) * D_ + kq);
        *(float4*)(sZ + zb * ZSTR_ + kq) = v;
    }

    // ---- P init = b1 ----
    float P[NU_];
#pragma unroll
    for (int i = 0; i < NU_; ++i) {
        const int j = sub + (i << 4);
        P[i] = (j < HID_) ? b1[r * HID_ + j] : 0.f;
    }

    // ---- stage w chunk 0 (k dwords 0..31 -> w1 cols 2..33), coalesced float2 ----
#pragma unroll
    for (int p = 0; p < 17; ++p) {
        const int idx = p * 256 + t;           // 0..4351 = 272*16 float2 slots
        const int j   = idx >> 4;
        const int kk  = (idx & 15) << 1;       // dword pair offset 0..30
        float2 v = make_float2(0.f, 0.f);
        if (j < HID_) v = *(const float2*)(w1r + j * IN_ + 2 + kk);
        *(float2*)(sW + j * WSTR_ + kk) = v;
    }
    __syncthreads();

    // ---- cooperative GEMM: P[i] += dot(w1[j][2+k], z[b][k]) over 4 k-chunks ----
    for (int c = 0; c < 4; ++c) {
        float4 zv[8];
#pragma unroll
        for (int kk = 0; kk < 8; ++kk)
            zv[kk] = *(const float4*)(sZ + g * ZSTR_ + c * 32 + kk * 4);
#pragma unroll
        for (int i = 0; i < NU_; ++i) {
            const int j = sub + (i << 4);
            float acc = P[i];
#pragma unroll
            for (int kk = 0; kk < 8; ++kk) {
                const float4 wv = *(const float4*)(sW + j * WSTR_ + kk * 4);
                acc = fmaf(wv.x, zv[kk].x, acc);
                acc = fmaf(wv.y, zv[kk].y, acc);
                acc = fmaf(wv.z, zv[kk].z, acc);
                acc = fmaf(wv.w, zv[kk].w, acc);
            }
            P[i] = acc;
        }
        if (c < 3) {
            __syncthreads();
#pragma unroll
            for (int p = 0; p < 17; ++p) {
                const int idx = p * 256 + t;
                const int j   = idx >> 4;
                const int kk  = (idx & 15) << 1;
                float2 v = make_float2(0.f, 0.f);
                if (j < HID_) v = *(const float2*)(w1r + j * IN_ + 2 + (c + 1) * 32 + kk);
                *(float2*)(sW + j * WSTR_ + kk) = v;
            }
            __syncthreads();
        }
    }

    // ---- per-unit params A (t-col), C (y-col), W (w2), small uncoalesced loads ----
    float A[NU_], C[NU_], W[NU_];
#pragma unroll
    for (int i = 0; i < NU_; ++i) {
        const int j = sub + (i << 4);
        if (j < HID_) {
            const float2 ac = *(const float2*)(w1r + j * IN_);
            A[i] = ac.x; C[i] = ac.y;
            W[i] = w2[r * HID_ + j];
        } else {
            A[i] = 0.f; C[i] = 0.f; W[i] = 0.f; P[i] = 0.f;
        }
    }
    const float b2r = b2[r];

    // ---- f-eval: softplus( sum_j W_j*relu(P_j + tt*A_j + y*C_j) + b2 ) * te ----
    auto feval = [&](float t1, float yv) -> float {
        const float tt = t1 * te;
        float d0 = 0.f, d1 = 0.f;
#pragma unroll
        for (int i = 0; i < NU_; ++i) {
            const float hv = fmaf(tt, A[i], fmaf(yv, C[i], P[i]));
            if (i & 1) d1 = fmaf(W[i], fmaxf(hv, 0.f), d1);
            else       d0 = fmaf(W[i], fmaxf(hv, 0.f), d0);
        }
        const float dot = dpp_add16(d0 + d1);
        return softplus_fast(dot + b2r) * te;
    };

    // ---- dopri5, fp32 replication; groups masked, wave-uniform exit ----
    float tc = 0.f, y = 0.f, h = H0_;
    float fy = feval(0.f, 0.f);
    bool done = false;
    for (int s = 0; s < MAXSTEPS_; ++s) {
        if (__ballot(!done) == 0ULL) break;
        h = fminf(h, 1.0f - tc);
        const float k1 = fy;
        const float k2 = feval(tc + 0.2f * h, y + h * (0.2f * k1));
        const float k3 = feval(tc + 0.3f * h, y + h * (3.f/40.f * k1 + 9.f/40.f * k2));
        const float k4 = feval(tc + 0.8f * h, y + h * (44.f/45.f * k1 - 56.f/15.f * k2 + 32.f/9.f * k3));
        const float k5 = feval(tc + 8.f/9.f * h,
            y + h * (19372.f/6561.f * k1 - 25360.f/2187.f * k2 + 64448.f/6561.f * k3 - 212.f/729.f * k4));
        const float k6 = feval(tc + h,
            y + h * (9017.f/3168.f * k1 - 355.f/33.f * k2 + 46732.f/5247.f * k3 + 49.f/176.f * k4 - 5103.f/18656.f * k5));
        const float y5 = y + h * (35.f/384.f * k1 + 500.f/1113.f * k3 + 125.f/192.f * k4
                                  - 2187.f/6784.f * k5 + 11.f/84.f * k6);
        const float k7 = feval(tc + h, y5);
        const float err = h * (71.f/57600.f * k1 - 71.f/16695.f * k3 + 71.f/1920.f * k4
                               - 17253.f/339200.f * k5 + 22.f/525.f * k6 - 1.f/40.f * k7);
        const float scale = ATOL_ + RTOL_ * fmaxf(fabsf(y), fabsf(y5));
        const float ratio = err / scale;
        const float en = sqrtf(ratio * ratio);
        const bool accept = (en <= 1.0f) && (!done);
        const float fac = fminf(fmaxf(0.9f * exp2f(-0.2f * log2f(fmaxf(en, 1e-10f))), 0.2f), 10.f);
        const float t_n = accept ? tc + h : tc;
        y  = accept ? y5 : y;
        fy = accept ? k7 : fy;
        h  = done ? h : h * fac;
        tc = t_n;
        done = done || (t_n >= 1.0f - 1e-9f);
    }

    const float yT = y;
    const float hazf = feval(1.0f, yT);
    const float t_rec = (te != 0.f) ? (1.f / te) : 0.f;

    if (sub == 0) {
        out[r * B_ + b] = t_rec * hazf;               // haz: [R,1,B]
        const int base = R_ * B_ + (r * B_ + b) * 2;  // chf: [R,B,2,1]
        out[base + 0] = 0.f;
        out[base + 1] = yT;
    }
}

extern "C" void kernel_launch(void* const* d_in, const int* in_sizes, int n_in,
                              void* d_out, int out_size, void* d_ws, size_t ws_size,
                              hipStream_t stream) {
    const float* z      = (const float*)d_in[0];
    const float* t_eval = (const float*)d_in[1];
    const float* w1     = (const float*)d_in[2];
    const float* b1     = (const float*)d_in[3];
    const float* w2     = (const float*)d_in[4];
    const float* b2     = (const float*)d_in[5];
    float* out = (float*)d_out;

    dim3 grid(512), block(256);   // 512 blocks = 2 risks x 256 b-tiles of 16
    hipLaunchKernelGGL(cr_kernel, grid, block, 0, stream,
                       z, t_eval, w1, b1, w2, b2, out);
}

// Round 4
// 95.441 us; speedup vs baseline: 2.5962x; 2.5962x over previous
//
#include <hip/hip_runtime.h>
#include <math.h>

// CompetingRisks: B=4096, D=128, R=2.
// K1: tiled GEMM  P[r][b][j] = b1[j] + dot(z[b], w1[r][j][2:130])  -> ws
//     + packs A=w1[..][0], C=w1[..][1], W=w2 into ws (coalesced for K2).
// K2: dopri5 scalar ODE, 16 tasks/block, 16 lanes/task; per-feval:
//     17 units/lane + 4-op DPP reduce + fast softplus. (R1 structure, 68 VGPR.)

#define B_ 4096
#define R_ 2
#define D_ 128
#define IN_ 130
#define HID_ 260
#define MAXSTEPS_ 16
#define H0_ 0.05f
#define RTOL_ 1e-3f
#define ATOL_ 1e-3f
#define NU_ 17        // units per lane in K2: j = sub + 16*i
#define JP_ 272       // padded j stride in ws (16-aligned)
#define LSTR_ 132     // LDS row stride (dwords): 2-way banks, float4-aligned

// ws layout (floats): P [R][B][JP_]  then  ACW [R][3][JP_]
#define WS_P_      0
#define WS_ACW_    (R_ * B_ * JP_)

// ---------------- K1: GEMM ----------------
__global__ __launch_bounds__(256) void k1_gemm(
    const float* __restrict__ z, const float* __restrict__ w1,
    const float* __restrict__ b1, const float* __restrict__ w2,
    float* __restrict__ ws)
{
    __shared__ float sW[64 * LSTR_];   // 33792 B
    __shared__ float sZ[64 * LSTR_];   // 33792 B

    const int t  = threadIdx.x;
    const int r  = blockIdx.x / 320;          // 640 blocks = 2 * 5 * 64
    const int jt = (blockIdx.x % 320) >> 6;   // 0..4
    const int bt = blockIdx.x & 63;           // 0..63
    const int j0 = jt * 64;
    const int b0 = bt * 64;

    const float* w1r = w1 + r * HID_ * IN_;

    // ---- ACW pack (only bt==0 blocks; 10 blocks total do this) ----
    if (bt == 0 && t < 64) {
        const int j = j0 + t;
        if (j < HID_) {
            const float2 ac = *(const float2*)(w1r + j * IN_);
            float* acw = ws + WS_ACW_ + r * 3 * JP_;
            acw[0 * JP_ + j] = ac.x;
            acw[1 * JP_ + j] = ac.y;
            acw[2 * JP_ + j] = w2[r * HID_ + j];
        }
    }

    // ---- stage w tile: 64 rows x 128 cols (w1 cols 2..129), float2 coalesced ----
#pragma unroll
    for (int p = 0; p < 16; ++p) {
        const int slot = p * 256 + t;         // 0..4095
        const int jr   = slot >> 6;
        const int c2   = (slot & 63) << 1;    // dword col 0..126
        const int j    = j0 + jr;
        float2 v = make_float2(0.f, 0.f);
        if (j < HID_) v = *(const float2*)(w1r + j * IN_ + 2 + c2);
        *(float2*)(sW + jr * LSTR_ + c2) = v;
    }
    // ---- stage z tile: 64 rows x 128, float4 coalesced ----
#pragma unroll
    for (int p = 0; p < 8; ++p) {
        const int slot = p * 256 + t;         // 0..2047
        const int br   = slot >> 5;
        const int c4   = (slot & 31) << 2;
        const float4 v = *(const float4*)(z + (b0 + br) * D_ + c4);
        *(float4*)(sZ + br * LSTR_ + c4) = v;
    }
    __syncthreads();

    // ---- 4x4 register blocking: thread -> j in {tj+16*jj}, b in {4*tb+bb} ----
    const int tj = t & 15;
    const int tb = t >> 4;
    float acc[4][4];
#pragma unroll
    for (int a = 0; a < 4; ++a)
#pragma unroll
        for (int c = 0; c < 4; ++c) acc[a][c] = 0.f;

    const float* pw = sW + tj * LSTR_;
    const float* pz = sZ + (tb * 4) * LSTR_;
#pragma unroll 2
    for (int k = 0; k < D_; k += 4) {
        float4 wv0 = *(const float4*)(pw + 0 * 16 * LSTR_ + k);
        float4 wv1 = *(const float4*)(pw + 1 * 16 * LSTR_ + k);
        float4 wv2 = *(const float4*)(pw + 2 * 16 * LSTR_ + k);
        float4 wv3 = *(const float4*)(pw + 3 * 16 * LSTR_ + k);
        float4 zv0 = *(const float4*)(pz + 0 * LSTR_ + k);
        float4 zv1 = *(const float4*)(pz + 1 * LSTR_ + k);
        float4 zv2 = *(const float4*)(pz + 2 * LSTR_ + k);
        float4 zv3 = *(const float4*)(pz + 3 * LSTR_ + k);
#define FMA4(A, WV, ZV) \
        A = fmaf(WV.x, ZV.x, A); A = fmaf(WV.y, ZV.y, A); \
        A = fmaf(WV.z, ZV.z, A); A = fmaf(WV.w, ZV.w, A);
        FMA4(acc[0][0], wv0, zv0) FMA4(acc[0][1], wv0, zv1)
        FMA4(acc[0][2], wv0, zv2) FMA4(acc[0][3], wv0, zv3)
        FMA4(acc[1][0], wv1, zv0) FMA4(acc[1][1], wv1, zv1)
        FMA4(acc[1][2], wv1, zv2) FMA4(acc[1][3], wv1, zv3)
        FMA4(acc[2][0], wv2, zv0) FMA4(acc[2][1], wv2, zv1)
        FMA4(acc[2][2], wv2, zv2) FMA4(acc[2][3], wv2, zv3)
        FMA4(acc[3][0], wv3, zv0) FMA4(acc[3][1], wv3, zv1)
        FMA4(acc[3][2], wv3, zv2) FMA4(acc[3][3], wv3, zv3)
#undef FMA4
    }

    // ---- write P (+b1), guarded to j<260; coalesced across tj ----
#pragma unroll
    for (int jj = 0; jj < 4; ++jj) {
        const int j = j0 + tj + 16 * jj;
        if (j < HID_) {
            const float bj = b1[r * HID_ + j];
#pragma unroll
            for (int bb = 0; bb < 4; ++bb) {
                const int b = b0 + tb * 4 + bb;
                ws[WS_P_ + (r * B_ + b) * JP_ + j] = acc[jj][bb] + bj;
            }
        }
    }
}

// ---------------- K2: ODE solve ----------------
__device__ __forceinline__ float dpp_add16(float v) {
    int y;
    y = __builtin_amdgcn_update_dpp(0, __float_as_int(v), 0xB1, 0xF, 0xF, false);  // xor1
    v += __int_as_float(y);
    y = __builtin_amdgcn_update_dpp(0, __float_as_int(v), 0x4E, 0xF, 0xF, false);  // xor2
    v += __int_as_float(y);
    y = __builtin_amdgcn_update_dpp(0, __float_as_int(v), 0x124, 0xF, 0xF, false); // row_ror:4
    v += __int_as_float(y);
    y = __builtin_amdgcn_update_dpp(0, __float_as_int(v), 0x128, 0xF, 0xF, false); // row_ror:8
    v += __int_as_float(y);
    return v;
}

__device__ __forceinline__ float softplus_fast(float x) {
    const float q  = exp2f(-1.4426950408889634f * fabsf(x));
    const float lg = 0.6931471805599453f * log2f(1.0f + q);
    return fmaxf(x, 0.0f) + lg;
}

__global__ __launch_bounds__(256) void k2_solve(
    const float* __restrict__ t_eval, const float* __restrict__ b2,
    const float* __restrict__ ws, float* __restrict__ out)
{
    const int sub = threadIdx.x & 15;
    const int T   = blockIdx.x * 16 + (threadIdx.x >> 4);
    const int r   = T >> 12;
    const int b   = T & (B_ - 1);

    const float te = t_eval[b];

    // ---- coalesced parameter loads from ws ----
    float P[NU_], A[NU_], C[NU_], W[NU_];
    const float* pp  = ws + WS_P_ + (r * B_ + b) * JP_;
    const float* acw = ws + WS_ACW_ + r * 3 * JP_;
#pragma unroll
    for (int i = 0; i < NU_; ++i) {
        const int j = sub + (i << 4);
        if (j < HID_) {
            P[i] = pp[j];
            A[i] = acw[0 * JP_ + j];
            C[i] = acw[1 * JP_ + j];
            W[i] = acw[2 * JP_ + j];
        } else {
            P[i] = A[i] = C[i] = W[i] = 0.f;
        }
    }
    const float b2r = b2[r];

    auto feval = [&](float t1, float yv) -> float {
        const float tt = t1 * te;
        float d0 = 0.f, d1 = 0.f;
#pragma unroll
        for (int i = 0; i < NU_; ++i) {
            const float hv = fmaf(tt, A[i], fmaf(yv, C[i], P[i]));
            if (i & 1) d1 = fmaf(W[i], fmaxf(hv, 0.f), d1);
            else       d0 = fmaf(W[i], fmaxf(hv, 0.f), d0);
        }
        const float dot = dpp_add16(d0 + d1);
        return softplus_fast(dot + b2r) * te;
    };

    // ---- dopri5, fp32 replication; groups masked, wave-uniform exit ----
    float tc = 0.f, y = 0.f, h = H0_;
    float fy = feval(0.f, 0.f);
    bool done = false;
    for (int s = 0; s < MAXSTEPS_; ++s) {
        if (__ballot(!done) == 0ULL) break;
        h = fminf(h, 1.0f - tc);
        const float k1 = fy;
        const float k2 = feval(tc + 0.2f * h, y + h * (0.2f * k1));
        const float k3 = feval(tc + 0.3f * h, y + h * (3.f/40.f * k1 + 9.f/40.f * k2));
        const float k4 = feval(tc + 0.8f * h, y + h * (44.f/45.f * k1 - 56.f/15.f * k2 + 32.f/9.f * k3));
        const float k5 = feval(tc + 8.f/9.f * h,
            y + h * (19372.f/6561.f * k1 - 25360.f/2187.f * k2 + 64448.f/6561.f * k3 - 212.f/729.f * k4));
        const float k6 = feval(tc + h,
            y + h * (9017.f/3168.f * k1 - 355.f/33.f * k2 + 46732.f/5247.f * k3 + 49.f/176.f * k4 - 5103.f/18656.f * k5));
        const float y5 = y + h * (35.f/384.f * k1 + 500.f/1113.f * k3 + 125.f/192.f * k4
                                  - 2187.f/6784.f * k5 + 11.f/84.f * k6);
        const float k7 = feval(tc + h, y5);
        const float err = h * (71.f/57600.f * k1 - 71.f/16695.f * k3 + 71.f/1920.f * k4
                               - 17253.f/339200.f * k5 + 22.f/525.f * k6 - 1.f/40.f * k7);
        const float scale = ATOL_ + RTOL_ * fmaxf(fabsf(y), fabsf(y5));
        const float ratio = err / scale;
        const float en = sqrtf(ratio * ratio);
        const bool accept = (en <= 1.0f) && (!done);
        const float fac = fminf(fmaxf(0.9f * exp2f(-0.2f * log2f(fmaxf(en, 1e-10f))), 0.2f), 10.f);
        const float t_n = accept ? tc + h : tc;
        y  = accept ? y5 : y;
        fy = accept ? k7 : fy;
        h  = done ? h : h * fac;
        tc = t_n;
        done = done || (t_n >= 1.0f - 1e-9f);
    }

    const float yT = y;
    const float hazf = feval(1.0f, yT);
    const float t_rec = (te != 0.f) ? (1.f / te) : 0.f;

    if (sub == 0) {
        out[r * B_ + b] = t_rec * hazf;               // haz: [R,1,B]
        const int base = R_ * B_ + (r * B_ + b) * 2;  // chf: [R,B,2,1]
        out[base + 0] = 0.f;
        out[base + 1] = yT;
    }
}

extern "C" void kernel_launch(void* const* d_in, const int* in_sizes, int n_in,
                              void* d_out, int out_size, void* d_ws, size_t ws_size,
                              hipStream_t stream) {
    const float* z      = (const float*)d_in[0];
    const float* t_eval = (const float*)d_in[1];
    const float* w1     = (const float*)d_in[2];
    const float* b1     = (const float*)d_in[3];
    const float* w2     = (const float*)d_in[4];
    const float* b2     = (const float*)d_in[5];
    float* out = (float*)d_out;
    float* ws  = (float*)d_ws;   // needs (2*4096*272 + 2*3*272)*4 = ~8.9 MB

    hipLaunchKernelGGL(k1_gemm, dim3(640), dim3(256), 0, stream,
                       z, w1, b1, w2, ws);
    hipLaunchKernelGGL(k2_solve, dim3(512), dim3(256), 0, stream,
                       t_eval, b2, ws, out);
}